// Round 22
// baseline (131.966 us; speedup 1.0000x reference)
//
#include <hip/hip_runtime.h>
#include <float.h>

#define L_TOK 65536
#define DIM   64
#define NCODE 1024
#define KCAP  16

typedef __attribute__((ext_vector_type(8))) short bf16x8;
typedef __attribute__((ext_vector_type(4))) float f32x4;

__device__ __forceinline__ unsigned short f2bf(float f) {
    unsigned u = __float_as_uint(f);
    u += 0x7FFF + ((u >> 16) & 1);          // RNE to bf16 (no NaN inputs)
    return (unsigned short)(u >> 16);
}
__device__ __forceinline__ unsigned f2ord(float f) {   // order-preserving uint
    unsigned u = __float_as_uint(f);
    return (u & 0x80000000u) ? ~u : (u | 0x80000000u);
}

// ---------------------------------------------------------------------------
// Kernel A: per-code ||e||^2 (exact fp32 chain) + bf16 copy of embedding.
// ---------------------------------------------------------------------------
__global__ __launch_bounds__(256) void esum_kernel(const float* __restrict__ emb,
                                                   float* __restrict__ esum,
                                                   unsigned short* __restrict__ eb) {
    int n = blockIdx.x * 256 + threadIdx.x;
    if (n >= NCODE) return;
    const float* e = emb + ((size_t)n << 6);
    float s = 0.f;
#pragma unroll
    for (int k = 0; k < DIM; ++k) s = fmaf(e[k], e[k], s);
    esum[n] = s;
#pragma unroll
    for (int k = 0; k < DIM; ++k) eb[(n << 6) + k] = f2bf(e[k]);
}

// ---------------------------------------------------------------------------
// Kernel P: per-token exact ||z||^2 (reference-bitwise chain) + bf16 margin
// M = sum|z| * 2.4e-5 + 6e-5 (absmax 0.0 in r16-r21).
// ---------------------------------------------------------------------------
__global__ __launch_bounds__(256) void prep_kernel(const float* __restrict__ z,
                                                   float* __restrict__ zs_out,
                                                   float* __restrict__ marg_out) {
    __shared__ float zl[256][65];
    const int t  = threadIdx.x;
    const int bb = blockIdx.x * 256;
    for (int i = t; i < 4096; i += 256) {
        float4 v = ((const float4*)(z + ((size_t)bb << 6)))[i];
        int tok = i >> 4, k = (i & 15) * 4;
        zl[tok][k] = v.x; zl[tok][k+1] = v.y; zl[tok][k+2] = v.z; zl[tok][k+3] = v.w;
    }
    __syncthreads();
    float zs = 0.f, sa = 0.f;
#pragma unroll
    for (int k = 0; k < DIM; ++k) {
        float v = zl[t][k];
        zs = fmaf(v, v, zs);                // EXACT reference chain order
        sa += fabsf(v);
    }
    zs_out[bb + t]   = zs;
    marg_out[bb + t] = fmaf(sa, 2.4e-5f, 6e-5f);
}

// ---------------------------------------------------------------------------
// Kernel S: FUSED screen(min+ballot)+recheck, single pass over the problem.
// r21 waste: S1/S2/recheck = 3 kernels + global round-trips (thr_ord, cnt,
// cand, key) + init, forced by the code-half split. Fix: block = 128 tokens
// x ALL 1024 codes; wave covers 128 codes as 2 sequential chunks of 64
// (bq[4][2] = 32 VGPR/chunk -- the r20/r21 register-clean shape).
//  Phase 1: per-token min(q) over all codes (chunk loop), cross-wave merge
//           in LDS -> thr = min + marg. Block-local, no atomics.
//  Phase 2: bitwise-identical q (same LDS af, reloaded bq = same values,
//           same MFMA/fmaf sequence), ballot q<=thr, append to LDS lists.
//  Phase 3: exact recheck in-block: 4 slots/token over the LDS list, exact
//           reference-bitwise d, per-slot best key (ord(d)<<32|c) -> LDS ->
//           min merge = min-d-then-min-c = np.argmin first-wins.
//           cnt > KCAP -> in-block full exact scan (unconditional).
// Layouts r16-r21-validated. LDS ~29 KB, grid 512 = 2 blocks/CU.
// ---------------------------------------------------------------------------
__global__ __launch_bounds__(512, 2) void screen_kernel(const float* __restrict__ z,
                                                        const unsigned short* __restrict__ eb,
                                                        const float* __restrict__ esum,
                                                        const float* __restrict__ zs_g,
                                                        const float* __restrict__ marg,
                                                        const float* __restrict__ emb,
                                                        float* __restrict__ idx_out) {
    __shared__ unsigned short zbf[128 * 64];       // swizzled bf16 [tok][k], 16 KB
    __shared__ float minw[8][128];                 // 4 KB
    __shared__ float thr_l[128];                   // 0.5 KB
    __shared__ int   cnt_l[128];                   // 0.5 KB
    __shared__ unsigned short cand_l[128 * KCAP];  // 4 KB
    __shared__ unsigned long long bestk[4][128];   // 4 KB

    const int t    = threadIdx.x;
    const int lane = t & 63;
    const int w    = __builtin_amdgcn_readfirstlane(t >> 6);
    const int bb   = blockIdx.x * 128;
    char* zb = (char*)zbf;

    {   // stage z -> bf16 LDS, swizzled (r18-r21 verbatim)
        const int row = t >> 2, q = t & 3;
        const int sw  = (row & 7) << 4;
        const float* zr = z + ((size_t)(bb + row) << 6) + q * 16;
        bf16x8 c0, c1;
#pragma unroll
        for (int i = 0; i < 8; ++i) { c0[i] = (short)f2bf(zr[i]); c1[i] = (short)f2bf(zr[i + 8]); }
        *(bf16x8*)(zb + row * 128 + ((q * 32) ^ sw))      = c0;
        *(bf16x8*)(zb + row * 128 + ((q * 32 + 16) ^ sw)) = c1;
    }
    if (t < 128) cnt_l[t] = 0;
    __syncthreads();

    const int r16 = lane & 15;
    const int kg  = lane >> 4;

    // ---- phase 1: per-token min of q = es - 2a over all 1024 codes ----
    f32x4 mnq[8];
#pragma unroll
    for (int tile = 0; tile < 8; ++tile) {
        mnq[tile][0] = FLT_MAX; mnq[tile][1] = FLT_MAX;
        mnq[tile][2] = FLT_MAX; mnq[tile][3] = FLT_MAX;
    }
#pragma unroll
    for (int chunk = 0; chunk < 2; ++chunk) {
        bf16x8 bq[4][2];
        float  esv[4];
#pragma unroll
        for (int ct = 0; ct < 4; ++ct) {
            const int code = w * 128 + chunk * 64 + ct * 16 + r16;
            bq[ct][0] = *(const bf16x8*)(eb + ((size_t)code << 6) + kg * 8);
            bq[ct][1] = *(const bf16x8*)(eb + ((size_t)code << 6) + 32 + kg * 8);
            esv[ct]   = esum[code];
        }
#pragma unroll
        for (int tile = 0; tile < 8; ++tile) {
            const int arow = tile * 16 + r16;
            const int asw  = (arow & 7) << 4;
            bf16x8 af0 = *(const bf16x8*)(zb + arow * 128 + ((kg * 16) ^ asw));
            bf16x8 af1 = *(const bf16x8*)(zb + arow * 128 + ((64 + kg * 16) ^ asw));
#pragma unroll
            for (int ct = 0; ct < 4; ++ct) {
                f32x4 acc = {0.f, 0.f, 0.f, 0.f};
                acc = __builtin_amdgcn_mfma_f32_16x16x32_bf16(af0, bq[ct][0], acc, 0, 0, 0);
                acc = __builtin_amdgcn_mfma_f32_16x16x32_bf16(af1, bq[ct][1], acc, 0, 0, 0);
#pragma unroll
                for (int r = 0; r < 4; ++r) {
                    float q = fmaf(acc[r], -2.0f, esv[ct]);
                    mnq[tile][r] = fminf(mnq[tile][r], q);
                }
            }
        }
    }
#pragma unroll
    for (int tile = 0; tile < 8; ++tile)
#pragma unroll
        for (int r = 0; r < 4; ++r) {
            float v = mnq[tile][r];
            v = fminf(v, __shfl_xor(v, 1));
            v = fminf(v, __shfl_xor(v, 2));
            v = fminf(v, __shfl_xor(v, 4));
            v = fminf(v, __shfl_xor(v, 8));
            if (r16 == 0) minw[w][tile * 16 + kg * 4 + r] = v;
        }
    __syncthreads();
    if (t < 128) {
        float m = minw[0][t];
#pragma unroll
        for (int ww = 1; ww < 8; ++ww) m = fminf(m, minw[ww][t]);
        thr_l[t] = m + marg[bb + t];
    }
    __syncthreads();

    // ---- phase 2: bitwise-identical q, ballot, append to LDS lists ----
#pragma unroll
    for (int chunk = 0; chunk < 2; ++chunk) {
        bf16x8 bq[4][2];
        float  esv[4];
#pragma unroll
        for (int ct = 0; ct < 4; ++ct) {
            const int code = w * 128 + chunk * 64 + ct * 16 + r16;
            bq[ct][0] = *(const bf16x8*)(eb + ((size_t)code << 6) + kg * 8);
            bq[ct][1] = *(const bf16x8*)(eb + ((size_t)code << 6) + 32 + kg * 8);
            esv[ct]   = esum[code];
        }
#pragma unroll
        for (int tile = 0; tile < 8; ++tile) {
            const int arow = tile * 16 + r16;
            const int asw  = (arow & 7) << 4;
            bf16x8 af0 = *(const bf16x8*)(zb + arow * 128 + ((kg * 16) ^ asw));
            bf16x8 af1 = *(const bf16x8*)(zb + arow * 128 + ((64 + kg * 16) ^ asw));
            float thrv[4];
#pragma unroll
            for (int r = 0; r < 4; ++r) thrv[r] = thr_l[tile * 16 + kg * 4 + r];
#pragma unroll
            for (int ct = 0; ct < 4; ++ct) {
                f32x4 acc = {0.f, 0.f, 0.f, 0.f};
                acc = __builtin_amdgcn_mfma_f32_16x16x32_bf16(af0, bq[ct][0], acc, 0, 0, 0);
                acc = __builtin_amdgcn_mfma_f32_16x16x32_bf16(af1, bq[ct][1], acc, 0, 0, 0);
#pragma unroll
                for (int r = 0; r < 4; ++r) {
                    float q = fmaf(acc[r], -2.0f, esv[ct]);
                    unsigned long long mask = __ballot(q <= thrv[r]);
                    if (r16 == 0) {
                        unsigned bits = (unsigned)((mask >> (kg * 16)) & 0xFFFFull);
                        int tok = tile * 16 + kg * 4 + r;
                        while (bits) {
                            int b = __builtin_ctz(bits);
                            bits &= bits - 1;
                            int pos = atomicAdd(&cnt_l[tok], 1);
                            if (pos < KCAP)
                                cand_l[tok * KCAP + pos] =
                                    (unsigned short)(w * 128 + chunk * 64 + ct * 16 + b);
                        }
                    }
                }
            }
        }
    }
    __syncthreads();

    // ---- phase 3: exact recheck in-block (4 slots per token) ----
    {
        const int tok   = t & 127;
        const int slot  = t >> 7;
        const int token = bb + tok;
        const float* zr = z + ((size_t)token << 6);
        const float  zsx = zs_g[token];
        const int    n   = cnt_l[tok];

        unsigned long long best = ~0ull;
        if (n <= KCAP) {
            for (int j = slot; j < n; j += 4) {
                int c = cand_l[tok * KCAP + j];
                const float* er = emb + ((size_t)c << 6);
                float a = 0.f;
#pragma unroll
                for (int k = 0; k < DIM; ++k) a = fmaf(zr[k], er[k], a);
                float d = fmaf(a, -2.0f, zsx + esum[c]);     // reference-bitwise
                unsigned long long kk = ((unsigned long long)f2ord(d) << 32) | (unsigned)c;
                if (kk < best) best = kk;
            }
        } else {
            for (int c = slot; c < NCODE; c += 4) {          // unconditional fallback
                const float* er = emb + ((size_t)c << 6);
                float a = 0.f;
#pragma unroll
                for (int k = 0; k < DIM; ++k) a = fmaf(zr[k], er[k], a);
                float d = fmaf(a, -2.0f, zsx + esum[c]);
                unsigned long long kk = ((unsigned long long)f2ord(d) << 32) | (unsigned)c;
                if (kk < best) best = kk;
            }
        }
        bestk[slot][tok] = best;
    }
    __syncthreads();
    if (t < 128) {
        unsigned long long b = bestk[0][t];
        if (bestk[1][t] < b) b = bestk[1][t];
        if (bestk[2][t] < b) b = bestk[2][t];
        if (bestk[3][t] < b) b = bestk[3][t];
        idx_out[bb + t] = (float)(unsigned)(b & 0xFFFFFFFFull);
    }
}

// ---------------------------------------------------------------------------
// Kernel C: z_q_st + f64 loss partials (r15-style idx_f input, proven).
// ---------------------------------------------------------------------------
__global__ __launch_bounds__(256) void output_kernel(const float* __restrict__ z,
                                                     const float* __restrict__ emb,
                                                     const float* __restrict__ idx_f,
                                                     float* __restrict__ zq_out,
                                                     double* __restrict__ partials) {
    int gid = blockIdx.x * 256 + threadIdx.x;
    int l = gid >> 6;
    int k = gid & 63;
    int idx = (int)idx_f[l];

    float zv = z[gid];
    float ev = emb[(idx << 6) + k];
    float t    = ev - zv;
    float outv = zv + t;
    zq_out[gid] = outv;

    float sq = t * t;

    __shared__ double red[256];
    red[threadIdx.x] = (double)sq;
    __syncthreads();
    for (int s = 128; s > 0; s >>= 1) {
        if (threadIdx.x < s) red[threadIdx.x] += red[threadIdx.x + s];
        __syncthreads();
    }
    if (threadIdx.x == 0) partials[blockIdx.x] = red[0];
}

// ---------------------------------------------------------------------------
// Kernel D: final deterministic reduction (unchanged, proven).
// ---------------------------------------------------------------------------
__global__ __launch_bounds__(256) void loss_kernel(const double* __restrict__ partials,
                                                   float* __restrict__ loss_out) {
    __shared__ double red[256];
    int t = threadIdx.x;
    double s = 0.0;
    for (int i = 0; i < 64; ++i) s += partials[t * 64 + i];
    red[t] = s;
    __syncthreads();
    for (int st = 128; st > 0; st >>= 1) {
        if (t < st) red[t] += red[t + st];
        __syncthreads();
    }
    if (t == 0) {
        double m  = red[0] / (double)(L_TOK * DIM);
        float  mf = (float)m;
        loss_out[0] = 0.25f * mf + mf;
    }
}

extern "C" void kernel_launch(void* const* d_in, const int* in_sizes, int n_in,
                              void* d_out, int out_size, void* d_ws, size_t ws_size,
                              hipStream_t stream) {
    const float* z   = (const float*)d_in[0];
    const float* emb = (const float*)d_in[1];

    float* out   = (float*)d_out;
    float* zq    = out;                 // [0, 4194304)
    float* loss  = out + 4194304;       // [4194304]
    float* idxf  = out + 4194305;       // [4194305, 4259841)

    char* ws = (char*)d_ws;
    float*          esum     = (float*)ws;                    // @0       4 KB
    unsigned short* eb       = (unsigned short*)(ws + 8192);  // @8K    128 KB
    float*          zs       = (float*)(ws + 139264);         // @136K  256 KB
    float*          marg     = (float*)(ws + 401408);         // @392K  256 KB
    double*         partials = (double*)(ws + 663552);        // @648K  128 KB

    esum_kernel  <<<4,     256, 0, stream>>>(emb, esum, eb);
    prep_kernel  <<<256,   256, 0, stream>>>(z, zs, marg);
    screen_kernel<<<512,   512, 0, stream>>>(z, eb, esum, zs, marg, emb, idxf);
    output_kernel<<<16384, 256, 0, stream>>>(z, emb, idxf, zq, partials);
    loss_kernel  <<<1,     256, 0, stream>>>(partials, loss);
}

// Round 23
// 98.693 us; speedup vs baseline: 1.3371x; 1.3371x over previous
//
#include <hip/hip_runtime.h>
#include <float.h>

#define L_TOK 65536
#define DIM   64
#define NCODE 1024
#define KCAP  16

typedef __attribute__((ext_vector_type(8))) short bf16x8;
typedef __attribute__((ext_vector_type(4))) float f32x4;

__device__ __forceinline__ unsigned short f2bf(float f) {
    unsigned u = __float_as_uint(f);
    u += 0x7FFF + ((u >> 16) & 1);          // RNE to bf16 (no NaN inputs)
    return (unsigned short)(u >> 16);
}
__device__ __forceinline__ unsigned f2ord(float f) {   // order-preserving uint
    unsigned u = __float_as_uint(f);
    return (u & 0x80000000u) ? ~u : (u | 0x80000000u);
}
__device__ __forceinline__ float ord2f(unsigned o) {   // exact inverse
    unsigned u = (o & 0x80000000u) ? (o & 0x7FFFFFFFu) : ~o;
    return __uint_as_float(u);
}

// ---------------------------------------------------------------------------
// Kernel I: init key + thr_ord (custom kernel; hipMemsetAsync fills dispatch
// as ~41us fillBufferAligned kernels -- r20 evidence).
// ---------------------------------------------------------------------------
__global__ __launch_bounds__(256) void init_kernel(unsigned long long* __restrict__ key,
                                                   unsigned* __restrict__ thr_ord) {
    int i = blockIdx.x * 256 + threadIdx.x;
    key[i]     = ~0ull;
    thr_ord[i] = ~0u;
}

// ---------------------------------------------------------------------------
// Kernel A: per-code ||e||^2 (exact fp32 chain) + bf16 copy of embedding.
// ---------------------------------------------------------------------------
__global__ __launch_bounds__(256) void esum_kernel(const float* __restrict__ emb,
                                                   float* __restrict__ esum,
                                                   unsigned short* __restrict__ eb) {
    int n = blockIdx.x * 256 + threadIdx.x;
    if (n >= NCODE) return;
    const float* e = emb + ((size_t)n << 6);
    float s = 0.f;
#pragma unroll
    for (int k = 0; k < DIM; ++k) s = fmaf(e[k], e[k], s);
    esum[n] = s;
#pragma unroll
    for (int k = 0; k < DIM; ++k) eb[(n << 6) + k] = f2bf(e[k]);
}

// ---------------------------------------------------------------------------
// Kernel P: per-token exact ||z||^2 (reference-bitwise chain) + bf16 margin
// M = sum|z| * 2.4e-5 + 6e-5 (absmax 0.0 in r16-r22).
// ---------------------------------------------------------------------------
__global__ __launch_bounds__(256) void prep_kernel(const float* __restrict__ z,
                                                   float* __restrict__ zs_out,
                                                   float* __restrict__ marg_out) {
    __shared__ float zl[256][65];
    const int t  = threadIdx.x;
    const int bb = blockIdx.x * 256;
    for (int i = t; i < 4096; i += 256) {
        float4 v = ((const float4*)(z + ((size_t)bb << 6)))[i];
        int tok = i >> 4, k = (i & 15) * 4;
        zl[tok][k] = v.x; zl[tok][k+1] = v.y; zl[tok][k+2] = v.z; zl[tok][k+3] = v.w;
    }
    __syncthreads();
    float zs = 0.f, sa = 0.f;
#pragma unroll
    for (int k = 0; k < DIM; ++k) {
        float v = zl[t][k];
        zs = fmaf(v, v, zs);                // EXACT reference chain order
        sa += fabsf(v);
    }
    zs_out[bb + t]   = zs;
    marg_out[bb + t] = fmaf(sa, 2.4e-5f, 6e-5f);
}

// ---------------------------------------------------------------------------
// Screen1 (min pass): r21 VERBATIM -- register-clean shape proven at 101.9us.
// block = 128 tokens x code-half; wave owns 64 codes (bq[4][2] = 32 VGPR).
// ---------------------------------------------------------------------------
__global__ __launch_bounds__(512, 2) void screen1_kernel(const float* __restrict__ z,
                                                         const unsigned short* __restrict__ eb,
                                                         const float* __restrict__ esum,
                                                         unsigned* __restrict__ thr_ord) {
    __shared__ unsigned short zbf[128 * 64];   // swizzled bf16 [tok][k], 16 KB
    __shared__ float minw[8][128];             // 4 KB

    const int t    = threadIdx.x;
    const int lane = t & 63;
    const int w    = __builtin_amdgcn_readfirstlane(t >> 6);
    const int bb   = (blockIdx.x >> 1) * 128;
    const int ch   = blockIdx.x & 1;
    char* zb = (char*)zbf;

    {   // stage z -> bf16 LDS, swizzled (r18-r21 verbatim)
        const int row = t >> 2, q = t & 3;
        const int sw  = (row & 7) << 4;
        const float* zr = z + ((size_t)(bb + row) << 6) + q * 16;
        bf16x8 c0, c1;
#pragma unroll
        for (int i = 0; i < 8; ++i) { c0[i] = (short)f2bf(zr[i]); c1[i] = (short)f2bf(zr[i + 8]); }
        *(bf16x8*)(zb + row * 128 + ((q * 32) ^ sw))      = c0;
        *(bf16x8*)(zb + row * 128 + ((q * 32 + 16) ^ sw)) = c1;
    }

    const int r16 = lane & 15;
    const int kg  = lane >> 4;

    bf16x8 bq[4][2];
    float  esv[4];
#pragma unroll
    for (int ct = 0; ct < 4; ++ct) {
        const int code = ch * 512 + w * 64 + ct * 16 + r16;
        bq[ct][0] = *(const bf16x8*)(eb + ((size_t)code << 6) + kg * 8);
        bq[ct][1] = *(const bf16x8*)(eb + ((size_t)code << 6) + 32 + kg * 8);
        esv[ct]   = esum[code];
    }
    __syncthreads();

#pragma unroll
    for (int tile = 0; tile < 8; ++tile) {
        const int arow = tile * 16 + r16;
        const int asw  = (arow & 7) << 4;
        bf16x8 af0 = *(const bf16x8*)(zb + arow * 128 + ((kg * 16) ^ asw));
        bf16x8 af1 = *(const bf16x8*)(zb + arow * 128 + ((64 + kg * 16) ^ asw));
        f32x4 mnq = {FLT_MAX, FLT_MAX, FLT_MAX, FLT_MAX};
#pragma unroll
        for (int ct = 0; ct < 4; ++ct) {
            f32x4 acc = {0.f, 0.f, 0.f, 0.f};
            acc = __builtin_amdgcn_mfma_f32_16x16x32_bf16(af0, bq[ct][0], acc, 0, 0, 0);
            acc = __builtin_amdgcn_mfma_f32_16x16x32_bf16(af1, bq[ct][1], acc, 0, 0, 0);
#pragma unroll
            for (int r = 0; r < 4; ++r) {
                float q = fmaf(acc[r], -2.0f, esv[ct]);
                mnq[r] = fminf(mnq[r], q);
            }
        }
#pragma unroll
        for (int r = 0; r < 4; ++r) {
            float v = mnq[r];
            v = fminf(v, __shfl_xor(v, 1));
            v = fminf(v, __shfl_xor(v, 2));
            v = fminf(v, __shfl_xor(v, 4));
            v = fminf(v, __shfl_xor(v, 8));
            if (r16 == 0) minw[w][tile * 16 + kg * 4 + r] = v;
        }
    }
    __syncthreads();
    if (t < 128) {
        float m = minw[0][t];
#pragma unroll
        for (int ww = 1; ww < 8; ++ww) m = fminf(m, minw[ww][t]);
        atomicMin(&thr_ord[bb + t], f2ord(m));
    }
}

// ---------------------------------------------------------------------------
// Screen2R: ballot pass (r21 screen2 body VERBATIM -- register-clean) with
// candidates in LDS, then fused in-block exact recheck (fresh regs after
// barrier). Each half-block atomicMins its best key (ord(d)<<32|c) into the
// global key[]: min-d-then-min-c == np.argmin first-wins, order-independent
// across halves. cnt > KCAP -> in-block full exact scan of this half's
// codes (the other half's block covers its own -- union is complete).
// ---------------------------------------------------------------------------
__global__ __launch_bounds__(512, 2) void screen2r_kernel(const float* __restrict__ z,
                                                          const unsigned short* __restrict__ eb,
                                                          const float* __restrict__ esum,
                                                          const float* __restrict__ zs_g,
                                                          const float* __restrict__ marg,
                                                          const unsigned* __restrict__ thr_ord,
                                                          const float* __restrict__ emb,
                                                          unsigned long long* __restrict__ key) {
    __shared__ unsigned short zbf[128 * 64];       // 16 KB
    __shared__ float thr_l[128];                   // 0.5 KB
    __shared__ int   cnt_l[128];                   // 0.5 KB
    __shared__ unsigned short cand_l[128 * KCAP];  // 4 KB
    __shared__ unsigned long long bestk[4][128];   // 4 KB

    const int t    = threadIdx.x;
    const int lane = t & 63;
    const int w    = __builtin_amdgcn_readfirstlane(t >> 6);
    const int bb   = (blockIdx.x >> 1) * 128;
    const int ch   = blockIdx.x & 1;
    char* zb = (char*)zbf;

    {   // stage z -> bf16 LDS, swizzled (identical to screen1 -> same bits)
        const int row = t >> 2, q = t & 3;
        const int sw  = (row & 7) << 4;
        const float* zr = z + ((size_t)(bb + row) << 6) + q * 16;
        bf16x8 c0, c1;
#pragma unroll
        for (int i = 0; i < 8; ++i) { c0[i] = (short)f2bf(zr[i]); c1[i] = (short)f2bf(zr[i + 8]); }
        *(bf16x8*)(zb + row * 128 + ((q * 32) ^ sw))      = c0;
        *(bf16x8*)(zb + row * 128 + ((q * 32 + 16) ^ sw)) = c1;
    }
    if (t < 128) {
        thr_l[t] = ord2f(thr_ord[bb + t]) + marg[bb + t];
        cnt_l[t] = 0;
    }

    const int r16 = lane & 15;
    const int kg  = lane >> 4;

    bf16x8 bq[4][2];
    float  esv[4];
#pragma unroll
    for (int ct = 0; ct < 4; ++ct) {
        const int code = ch * 512 + w * 64 + ct * 16 + r16;
        bq[ct][0] = *(const bf16x8*)(eb + ((size_t)code << 6) + kg * 8);
        bq[ct][1] = *(const bf16x8*)(eb + ((size_t)code << 6) + 32 + kg * 8);
        esv[ct]   = esum[code];
    }
    __syncthreads();

#pragma unroll
    for (int tile = 0; tile < 8; ++tile) {
        const int arow = tile * 16 + r16;
        const int asw  = (arow & 7) << 4;
        bf16x8 af0 = *(const bf16x8*)(zb + arow * 128 + ((kg * 16) ^ asw));
        bf16x8 af1 = *(const bf16x8*)(zb + arow * 128 + ((64 + kg * 16) ^ asw));
        float thrv[4];
#pragma unroll
        for (int r = 0; r < 4; ++r) thrv[r] = thr_l[tile * 16 + kg * 4 + r];
#pragma unroll
        for (int ct = 0; ct < 4; ++ct) {
            f32x4 acc = {0.f, 0.f, 0.f, 0.f};
            acc = __builtin_amdgcn_mfma_f32_16x16x32_bf16(af0, bq[ct][0], acc, 0, 0, 0);
            acc = __builtin_amdgcn_mfma_f32_16x16x32_bf16(af1, bq[ct][1], acc, 0, 0, 0);
#pragma unroll
            for (int r = 0; r < 4; ++r) {
                float q = fmaf(acc[r], -2.0f, esv[ct]);
                unsigned long long mask = __ballot(q <= thrv[r]);
                if (r16 == 0) {
                    unsigned bits = (unsigned)((mask >> (kg * 16)) & 0xFFFFull);
                    int tok = tile * 16 + kg * 4 + r;
                    while (bits) {
                        int b = __builtin_ctz(bits);
                        bits &= bits - 1;
                        int pos = atomicAdd(&cnt_l[tok], 1);
                        if (pos < KCAP)
                            cand_l[tok * KCAP + pos] =
                                (unsigned short)(ch * 512 + w * 64 + ct * 16 + b);
                    }
                }
            }
        }
    }
    __syncthreads();

    // ---- fused exact recheck (4 slots per token, this half's candidates) ----
    {
        const int tok   = t & 127;
        const int slot  = t >> 7;
        const int token = bb + tok;
        const float* zr = z + ((size_t)token << 6);
        const float  zsx = zs_g[token];
        const int    n   = cnt_l[tok];

        unsigned long long best = ~0ull;
        if (n <= KCAP) {
            for (int j = slot; j < n; j += 4) {
                int c = cand_l[tok * KCAP + j];
                const float* er = emb + ((size_t)c << 6);
                float a = 0.f;
#pragma unroll
                for (int k = 0; k < DIM; ++k) a = fmaf(zr[k], er[k], a);
                float d = fmaf(a, -2.0f, zsx + esum[c]);     // reference-bitwise
                unsigned long long kk = ((unsigned long long)f2ord(d) << 32) | (unsigned)c;
                if (kk < best) best = kk;
            }
        } else {
            for (int c = ch * 512 + slot; c < ch * 512 + 512; c += 4) {  // half fallback
                const float* er = emb + ((size_t)c << 6);
                float a = 0.f;
#pragma unroll
                for (int k = 0; k < DIM; ++k) a = fmaf(zr[k], er[k], a);
                float d = fmaf(a, -2.0f, zsx + esum[c]);
                unsigned long long kk = ((unsigned long long)f2ord(d) << 32) | (unsigned)c;
                if (kk < best) best = kk;
            }
        }
        bestk[slot][tok] = best;
    }
    __syncthreads();
    if (t < 128) {
        unsigned long long b = bestk[0][t];
        if (bestk[1][t] < b) b = bestk[1][t];
        if (bestk[2][t] < b) b = bestk[2][t];
        if (bestk[3][t] < b) b = bestk[3][t];
        if (b != ~0ull) atomicMin(&key[bb + t], b);
    }
}

// ---------------------------------------------------------------------------
// Kernel C: z_q_st + f64 loss partials + idx extraction (r19/r21-proven).
// ---------------------------------------------------------------------------
__global__ __launch_bounds__(256) void output_kernel(const float* __restrict__ z,
                                                     const float* __restrict__ emb,
                                                     const unsigned long long* __restrict__ key,
                                                     float* __restrict__ idx_out,
                                                     float* __restrict__ zq_out,
                                                     double* __restrict__ partials) {
    int gid = blockIdx.x * 256 + threadIdx.x;
    int l = gid >> 6;
    int k = gid & 63;
    int idx = (int)(unsigned)(key[l] & 0xFFFFFFFFull);

    float zv = z[gid];
    float ev = emb[(idx << 6) + k];
    float t    = ev - zv;
    float outv = zv + t;
    zq_out[gid] = outv;
    if (k == 0) idx_out[l] = (float)idx;

    float sq = t * t;

    __shared__ double red[256];
    red[threadIdx.x] = (double)sq;
    __syncthreads();
    for (int s = 128; s > 0; s >>= 1) {
        if (threadIdx.x < s) red[threadIdx.x] += red[threadIdx.x + s];
        __syncthreads();
    }
    if (threadIdx.x == 0) partials[blockIdx.x] = red[0];
}

// ---------------------------------------------------------------------------
// Kernel D: final deterministic reduction (unchanged, proven).
// ---------------------------------------------------------------------------
__global__ __launch_bounds__(256) void loss_kernel(const double* __restrict__ partials,
                                                   float* __restrict__ loss_out) {
    __shared__ double red[256];
    int t = threadIdx.x;
    double s = 0.0;
    for (int i = 0; i < 64; ++i) s += partials[t * 64 + i];
    red[t] = s;
    __syncthreads();
    for (int st = 128; st > 0; st >>= 1) {
        if (t < st) red[t] += red[t + st];
        __syncthreads();
    }
    if (t == 0) {
        double m  = red[0] / (double)(L_TOK * DIM);
        float  mf = (float)m;
        loss_out[0] = 0.25f * mf + mf;
    }
}

extern "C" void kernel_launch(void* const* d_in, const int* in_sizes, int n_in,
                              void* d_out, int out_size, void* d_ws, size_t ws_size,
                              hipStream_t stream) {
    const float* z   = (const float*)d_in[0];
    const float* emb = (const float*)d_in[1];

    float* out   = (float*)d_out;
    float* zq    = out;                 // [0, 4194304)
    float* loss  = out + 4194304;       // [4194304]
    float* idxf  = out + 4194305;       // [4194305, 4259841)

    char* ws = (char*)d_ws;
    float*              esum     = (float*)ws;                          // @0       4 KB
    unsigned short*     eb       = (unsigned short*)(ws + 8192);        // @8K    128 KB
    float*              zs       = (float*)(ws + 139264);               // @136K  256 KB
    float*              marg     = (float*)(ws + 401408);               // @392K  256 KB
    double*             partials = (double*)(ws + 663552);              // @648K  128 KB
    unsigned long long* key      = (unsigned long long*)(ws + 794624);  // @776K  512 KB
    unsigned*           thr_ord  = (unsigned*)(ws + 1318912);           // @1288K 256 KB

    init_kernel    <<<256,   256, 0, stream>>>(key, thr_ord);
    esum_kernel    <<<4,     256, 0, stream>>>(emb, esum, eb);
    prep_kernel    <<<256,   256, 0, stream>>>(z, zs, marg);
    screen1_kernel <<<1024,  512, 0, stream>>>(z, eb, esum, thr_ord);
    screen2r_kernel<<<1024,  512, 0, stream>>>(z, eb, esum, zs, marg, thr_ord, emb, key);
    output_kernel  <<<16384, 256, 0, stream>>>(z, emb, key, idxf, zq, partials);
    loss_kernel    <<<1,     256, 0, stream>>>(partials, loss);
}